// Round 2
// baseline (253.128 us; speedup 1.0000x reference)
//
#include <hip/hip_runtime.h>
#include <hip/hip_cooperative_groups.h>

namespace cg = cooperative_groups;

// Problem constants: B=32, N=1024, F_IN=D=128
#define B    32
#define N    1024
#define FIN  128
#define CHN  16      // chunks per batch
#define ROWS 64      // rows per chunk
#define GRID (B * CHN)  // 512 blocks, 2/CU with __launch_bounds__(256,2)

// ws float offsets
#define OFF_PASUM 0                        // [B][CHN][FIN] column partial sums
#define OFF_WPART (B * CHN * FIN)          // [B][CHN][FIN] weighted sums
#define OFF_M     (2 * B * CHN * FIN)      // [B][CHN]
#define OFF_L     (OFF_M + B * CHN)
#define OFF_S     (OFF_L + B * CHN)

__global__ __launch_bounds__(256, 2) void k_fused(
    const float* __restrict__ aq, const float* __restrict__ mask,
    const float* __restrict__ Wq, const float* __restrict__ bq,
    const float* __restrict__ Wk, const float* __restrict__ bk,
    const float* __restrict__ Wv, const float* __restrict__ bv,
    float* __restrict__ ws, float* __restrict__ out)
{
    cg::grid_group grid = cg::this_grid();
    const int b = blockIdx.x >> 4, ch = blockIdx.x & 15;
    const int tid = threadIdx.x;
    const int f = tid & 127, h = tid >> 7;

    // XOR-swizzled tile: float4 (r, j) lives at float4 index r*32 + (j ^ (r&31)).
    // Row float4 reads and column scalar reads are both <=2-way (free).
    __shared__ float tile[ROWS * FIN];       // 32 KB
    __shared__ float red[256], red2[256];
    __shared__ float asum_s[FIN], ksum_s[FIN], u_s[FIN];
    __shared__ float mp_s[ROWS];

    // ---- Phase 1: stage aq chunk into LDS + column partial sums ----
    {
        const float4* g4 = (const float4*)aq + ((size_t)b * N + ch * ROWS) * 32;
        float4* t4 = (float4*)tile;
        #pragma unroll
        for (int i = 0; i < 8; ++i) {
            int g = i * 256 + tid;
            int row = g >> 5, c4 = g & 31;
            t4[row * 32 + (c4 ^ (row & 31))] = g4[g];
        }
    }
    __syncthreads();
    {
        float acc = 0.f;
        #pragma unroll 8
        for (int i = 0; i < 32; ++i) {
            int r = h * 32 + i;
            acc += tile[r * FIN + ((((f >> 2) ^ (r & 31)) << 2) | (f & 3))];
        }
        red[tid] = acc;
        __syncthreads();
        if (tid < FIN)
            ws[OFF_PASUM + (b * CHN + ch) * FIN + f] = red[f] + red[f + 128];
    }
    __threadfence();
    grid.sync();

    // ---- Phase 2: asum -> ksum -> u, c (redundant per block; no extra sync) ----
    if (tid < FIN) {
        float a = 0.f;
        #pragma unroll
        for (int c = 0; c < CHN; ++c)
            a += ws[OFF_PASUM + (b * CHN + c) * FIN + f];
        asum_s[f] = a;
    }
    __syncthreads();
    {
        float ks = 0.f;
        #pragma unroll 8
        for (int i = 0; i < 64; ++i) {
            int fi = h * 64 + i;
            ks += asum_s[fi] * Wk[fi * FIN + f];   // coalesced over f
        }
        red[tid] = ks;
        __syncthreads();
        if (tid < FIN) ksum_s[f] = red[f] + red[f + 128] + 1024.f * bk[f];
        __syncthreads();
    }
    float c_b;
    {
        float uu = 0.f;
        #pragma unroll 8
        for (int i = 0; i < 64; ++i) {
            int d = h * 64 + i;
            uu += Wq[f * FIN + d] * ksum_s[d];     // L1-amortized strided reads
        }
        red[tid] = uu;
        red2[tid] = (h == 0) ? bq[f] * ksum_s[f] : 0.f;
        __syncthreads();
        if (tid < FIN) u_s[f] = red[f] + red[f + 128];
        for (int s = 128; s > 0; s >>= 1) {
            if (tid < s) red2[tid] += red2[tid + s];
            __syncthreads();
        }
        c_b = red2[0];
    }

    // ---- Phase 3: agg logits + chunk softmax stats (no serial exp chain) ----
    const float dkc = 0.08838834764831845f;  // 128^-0.5
    float aggv = -1e30f;
    {
        const int r = tid & 63, q = tid >> 6;
        const float4* t4 = (const float4*)tile;
        const float4* u4 = (const float4*)u_s;
        float acc = 0.f;
        #pragma unroll
        for (int jj = 0; jj < 8; ++jj) {
            int j = q * 8 + jj;
            float4 a = t4[r * 32 + (j ^ (r & 31))];
            float4 uu = u4[j];                     // wave-uniform broadcast
            acc += a.x * uu.x + a.y * uu.y + a.z * uu.z + a.w * uu.w;
        }
        red[tid] = acc;
    }
    __syncthreads();
    if (tid < ROWS) {
        float dot = red[tid] + red[tid + 64] + red[tid + 128] + red[tid + 192];
        float m = mask[b * N + ch * ROWS + tid];   // coalesced
        float raw = dkc * (dot + c_b);
        aggv = m * raw + (1.f - m) * (-1e9f);
        float Mc = aggv;
        #pragma unroll
        for (int off = 32; off > 0; off >>= 1)
            Mc = fmaxf(Mc, __shfl_xor(Mc, off));
        float p = __expf(aggv - Mc);
        float mp = m * p;
        mp_s[tid] = mp;
        float Lc = p, Sc = mp;
        #pragma unroll
        for (int off = 32; off > 0; off >>= 1) {
            Lc += __shfl_xor(Lc, off);
            Sc += __shfl_xor(Sc, off);
        }
        if (tid == 0) {
            ws[OFF_M + b * CHN + ch] = Mc;
            ws[OFF_L + b * CHN + ch] = Lc;
            ws[OFF_S + b * CHN + ch] = Sc;
        }
    }
    __syncthreads();
    {
        float w = 0.f;
        #pragma unroll 8
        for (int i = 0; i < 32; ++i) {
            int r = h * 32 + i;
            w += mp_s[r] * tile[r * FIN + ((((f >> 2) ^ (r & 31)) << 2) | (f & 3))];
        }
        red[tid] = w;
        __syncthreads();
        if (tid < FIN)
            ws[OFF_WPART + (b * CHN + ch) * FIN + f] = red[f] + red[f + 128];
    }
    __threadfence();
    grid.sync();

    // ---- Phase 4: cross-chunk combine, attn + context outputs ----
    float M = -3.0e38f;
    #pragma unroll
    for (int c = 0; c < CHN; ++c)
        M = fmaxf(M, ws[OFF_M + b * CHN + c]);    // uniform -> scalar loads
    float Em[CHN], L = 0.f, S = 0.f;
    #pragma unroll
    for (int c = 0; c < CHN; ++c) {
        float e = __expf(ws[OFF_M + b * CHN + c] - M);
        Em[c] = e;
        L += e * ws[OFF_L + b * CHN + c];
        S += e * ws[OFF_S + b * CHN + c];
    }
    const float invL = 1.f / L;
    // attn for this block's rows, straight from live registers
    if (tid < ROWS)
        out[b * N + ch * ROWS + tid] = __expf(aggv - M) * invL;
    // context by the ch==0 block of each batch
    if (ch == 0) {
        if (tid < FIN) {
            float w = 0.f;
            #pragma unroll
            for (int c = 0; c < CHN; ++c)
                w += Em[c] * ws[OFF_WPART + (b * CHN + c) * FIN + f];
            u_s[f] = w;
        }
        __syncthreads();
        float ctx = 0.f;
        #pragma unroll 8
        for (int i = 0; i < 64; ++i) {
            int fi = h * 64 + i;
            ctx += u_s[fi] * Wv[fi * FIN + f];    // coalesced over f
        }
        red[tid] = ctx;
        __syncthreads();
        if (tid < FIN)
            out[B * N + b * FIN + f] = (red[f] + red[f + 128]) * invL + S * invL * bv[f];
    }
}

extern "C" void kernel_launch(void* const* d_in, const int* in_sizes, int n_in,
                              void* d_out, int out_size, void* d_ws, size_t ws_size,
                              hipStream_t stream) {
    const float* aq   = (const float*)d_in[0];
    const float* mask = (const float*)d_in[1];
    const float* Wq   = (const float*)d_in[2];
    const float* bq   = (const float*)d_in[3];
    const float* Wk   = (const float*)d_in[4];
    const float* bk   = (const float*)d_in[5];
    const float* Wv   = (const float*)d_in[6];
    const float* bv   = (const float*)d_in[7];
    float* ws  = (float*)d_ws;
    float* out = (float*)d_out;

    void* args[] = {(void*)&aq, (void*)&mask, (void*)&Wq, (void*)&bq, (void*)&Wk,
                    (void*)&bk, (void*)&Wv, (void*)&bv, (void*)&ws, (void*)&out};
    hipLaunchCooperativeKernel((const void*)k_fused, dim3(GRID), dim3(256),
                               args, 0, stream);
}

// Round 3
// 101.046 us; speedup vs baseline: 2.5051x; 2.5051x over previous
//
#include <hip/hip_runtime.h>

// Problem constants: B=32, N=1024, F_IN=D=128
#define B    32
#define N    1024
#define FIN  128
#define CHN  16      // chunks per batch
#define ROWS 64      // rows per chunk
#define GRID (B * CHN)   // 512 blocks

// ws float offsets
#define OFF_PASUM 0                         // [B][CHN][FIN] column partial sums
#define OFF_P     (B * CHN * FIN)           // [B][N]  p = exp(agg - Mc), 0 for masked
#define OFF_WPART (OFF_P + B * N)           // [B][CHN][FIN] sum of m*p*aq
#define OFF_M     (OFF_WPART + B * CHN * FIN)  // [B][CHN]
#define OFF_L     (OFF_M + B * CHN)
#define OFF_S     (OFF_L + B * CHN)

// ---------------- K1: per-chunk column sums of atom_query -------------------
__global__ __launch_bounds__(256) void k_asum(const float* __restrict__ aq,
                                              float* __restrict__ ws) {
    const int b = blockIdx.x >> 4, ch = blockIdx.x & 15;
    const float4* g4 = (const float4*)aq + ((size_t)b * N + ch * ROWS) * 32;
    float4 acc = make_float4(0.f, 0.f, 0.f, 0.f);
    #pragma unroll
    for (int i = 0; i < 8; ++i) {             // rows i*8 + (tid>>5), col tid&31
        float4 v = g4[i * 256 + threadIdx.x];
        acc.x += v.x; acc.y += v.y; acc.z += v.z; acc.w += v.w;
    }
    __shared__ float4 sh[256];
    sh[threadIdx.x] = acc;
    __syncthreads();
    if (threadIdx.x < 32) {
        float4 r = sh[threadIdx.x];
        #pragma unroll
        for (int g = 1; g < 8; ++g) {
            float4 t = sh[g * 32 + threadIdx.x];
            r.x += t.x; r.y += t.y; r.z += t.z; r.w += t.w;
        }
        float4* outp = (float4*)(ws + OFF_PASUM) + (b * CHN + ch) * 32;
        outp[threadIdx.x] = r;
    }
}

// ---------------- K2: prep (redundant) + agg + chunk stats + wpart ----------
// grid 512 (= B*CHN), block 256. LDS: 32KB tile + ~3KB misc -> 4 blocks/CU.
__global__ __launch_bounds__(256) void k_main(
    const float* __restrict__ aq, const float* __restrict__ mask,
    const float* __restrict__ Wq, const float* __restrict__ bq,
    const float* __restrict__ Wk, const float* __restrict__ bk,
    float* __restrict__ ws)
{
    const int b = blockIdx.x >> 4, ch = blockIdx.x & 15;
    const int tid = threadIdx.x, f = tid & 127, h = tid >> 7;

    __shared__ float tile[ROWS * FIN];        // XOR-swizzled, 32 KB
    __shared__ float red[256];
    __shared__ float asum_s[FIN], ksum_s[FIN], u_s[FIN], mp_s[ROWS];
    __shared__ float c_sh;

    // Issue the tile staging loads FIRST; they drain while prep computes.
    float4 stage[8];
    const float4* g4 = (const float4*)aq + ((size_t)b * N + ch * ROWS) * 32;
    #pragma unroll
    for (int i = 0; i < 8; ++i) stage[i] = g4[i * 256 + tid];

    // ---- prep: asum -> ksum -> u, c (redundant per block; Wk/Wq are L2-hot)
    if (tid < FIN) {
        float a = 0.f;
        #pragma unroll
        for (int c = 0; c < CHN; ++c)
            a += ws[OFF_PASUM + (b * CHN + c) * FIN + f];
        asum_s[f] = a;
    }
    __syncthreads();
    {
        float ks = 0.f;
        #pragma unroll 8
        for (int i = 0; i < 64; ++i) {
            int fi = h * 64 + i;
            ks += asum_s[fi] * Wk[fi * FIN + f];      // coalesced over f
        }
        red[tid] = ks;
    }
    __syncthreads();
    if (tid < FIN) ksum_s[f] = red[f] + red[f + 128] + 1024.f * bk[f];
    __syncthreads();
    {
        float uu = 0.f;
        #pragma unroll 8
        for (int i = 0; i < 64; ++i) {
            int d = h * 64 + i;
            uu += Wq[f * FIN + d] * ksum_s[d];        // L2-amortized
        }
        red[tid] = uu;
    }
    __syncthreads();
    if (tid < FIN) u_s[f] = red[f] + red[f + 128];
    if (tid < 64) {
        float cc = bq[tid] * ksum_s[tid] + bq[tid + 64] * ksum_s[tid + 64];
        #pragma unroll
        for (int off = 32; off > 0; off >>= 1) cc += __shfl_xor(cc, off);
        if (tid == 0) c_sh = cc;
    }
    // ---- commit staged tile (swizzle: float4 (r,j) -> r*32 + (j ^ (r&31)))
    {
        float4* t4 = (float4*)tile;
        #pragma unroll
        for (int i = 0; i < 8; ++i) {
            int g = i * 256 + tid;
            int row = g >> 5, c4 = g & 31;
            t4[row * 32 + (c4 ^ (row & 31))] = stage[i];
        }
    }
    __syncthreads();

    // ---- all 64 row-dots in parallel: thread (r = tid&63, q = tid>>6)
    {
        const int r = tid & 63, q = tid >> 6;
        const float4* t4 = (const float4*)tile;
        const float4* u4 = (const float4*)u_s;
        float acc = 0.f;
        #pragma unroll
        for (int jj = 0; jj < 8; ++jj) {
            int j = q * 8 + jj;
            float4 a = t4[r * 32 + (j ^ (r & 31))];
            float4 uu = u4[j];                        // wave-uniform
            acc += a.x * uu.x + a.y * uu.y + a.z * uu.z + a.w * uu.w;
        }
        red[tid] = acc;
    }
    __syncthreads();
    if (tid < ROWS) {
        const float dkc = 0.08838834764831845f;       // 128^-0.5
        float dot = red[tid] + red[tid + 64] + red[tid + 128] + red[tid + 192];
        float m = mask[b * N + ch * ROWS + tid];      // coalesced
        float raw = dkc * (dot + c_sh);
        float aggv = m * raw + (1.f - m) * (-1e9f);
        float Mc = aggv;
        #pragma unroll
        for (int off = 32; off > 0; off >>= 1) Mc = fmaxf(Mc, __shfl_xor(Mc, off));
        float p = __expf(aggv - Mc);                  // masked rows -> exact 0
        float mp = m * p;
        ws[OFF_P + b * N + ch * ROWS + tid] = p;
        mp_s[tid] = mp;
        float Lc = p, Sc = mp;
        #pragma unroll
        for (int off = 32; off > 0; off >>= 1) {
            Lc += __shfl_xor(Lc, off);
            Sc += __shfl_xor(Sc, off);
        }
        if (tid == 0) {
            ws[OFF_M + b * CHN + ch] = Mc;
            ws[OFF_L + b * CHN + ch] = Lc;
            ws[OFF_S + b * CHN + ch] = Sc;
        }
    }
    __syncthreads();
    // ---- weighted column sums: wpart[f] = sum_r mp[r] * aq[r][f]
    {
        float w = 0.f;
        #pragma unroll 8
        for (int i = 0; i < 32; ++i) {
            int r = h * 32 + i;
            w += mp_s[r] * tile[r * FIN + ((((f >> 2) ^ (r & 31)) << 2) | (f & 3))];
        }
        red[tid] = w;
    }
    __syncthreads();
    if (tid < FIN)
        ws[OFF_WPART + (b * CHN + ch) * FIN + f] = red[f] + red[f + 128];
}

// ---------------- K3: cross-chunk combine + attn + context ------------------
// grid B, block 256.
__global__ __launch_bounds__(256) void k_final(const float* __restrict__ Wv,
                                               const float* __restrict__ bv,
                                               const float* __restrict__ ws,
                                               float* __restrict__ out) {
    const int b = blockIdx.x, tid = threadIdx.x, f = tid & 127, h = tid >> 7;
    float M = -3.0e38f;
    #pragma unroll
    for (int c = 0; c < CHN; ++c) M = fmaxf(M, ws[OFF_M + b * CHN + c]);
    float Em[CHN], L = 0.f, S = 0.f;
    #pragma unroll
    for (int c = 0; c < CHN; ++c) {
        float e = __expf(ws[OFF_M + b * CHN + c] - M);
        Em[c] = e;
        L += e * ws[OFF_L + b * CHN + c];
        S += e * ws[OFF_S + b * CHN + c];
    }
    const float invL = 1.f / L;
    // attn = p * Em[chunk] * invL   (4 rows per thread, coalesced)
    #pragma unroll
    for (int j = 0; j < 4; ++j) {
        int n = j * 256 + tid;                 // chunk = n>>6 = j*4 + (tid>>6)
        out[b * N + n] = ws[OFF_P + b * N + n] * Em[j * 4 + (tid >> 6)] * invL;
    }
    // context
    __shared__ float wsh[FIN];
    __shared__ float red[256];
    if (tid < FIN) {
        float w = 0.f;
        #pragma unroll
        for (int c = 0; c < CHN; ++c)
            w += Em[c] * ws[OFF_WPART + (b * CHN + c) * FIN + f];
        wsh[f] = w;
    }
    __syncthreads();
    {
        float ctx = 0.f;
        #pragma unroll 8
        for (int i = 0; i < 64; ++i) {
            int fi = h * 64 + i;
            ctx += wsh[fi] * Wv[fi * FIN + f];        // coalesced over f
        }
        red[tid] = ctx;
    }
    __syncthreads();
    if (tid < FIN)
        out[B * N + b * FIN + f] = (red[f] + red[f + 128]) * invL + S * invL * bv[f];
}

extern "C" void kernel_launch(void* const* d_in, const int* in_sizes, int n_in,
                              void* d_out, int out_size, void* d_ws, size_t ws_size,
                              hipStream_t stream) {
    const float* aq   = (const float*)d_in[0];
    const float* mask = (const float*)d_in[1];
    const float* Wq   = (const float*)d_in[2];
    const float* bq   = (const float*)d_in[3];
    const float* Wk   = (const float*)d_in[4];
    const float* bk   = (const float*)d_in[5];
    const float* Wv   = (const float*)d_in[6];
    const float* bv   = (const float*)d_in[7];
    float* ws  = (float*)d_ws;
    float* out = (float*)d_out;

    k_asum <<<GRID, 256, 0, stream>>>(aq, ws);
    k_main <<<GRID, 256, 0, stream>>>(aq, mask, Wq, bq, Wk, bk, ws);
    k_final<<<B,    256, 0, stream>>>(Wv, bv, ws, out);
}